// Round 1
// baseline (80.588 us; speedup 1.0000x reference)
//
#include <hip/hip_runtime.h>
#include <hip/hip_bf16.h>
#include <stdint.h>

#define NBATCH 16
#define SEQ 4096
#define DIM 256
#define MEM 40
#define KTOT 512            // interleaved K: k=2d -> x*W1, k=2d+1 -> h*W2
#define MTOT (NBATCH*SEQ)   // 65536 rows

typedef unsigned short u16;
typedef __attribute__((ext_vector_type(8))) short short8;
typedef __attribute__((ext_vector_type(4))) float f32x4;

typedef __attribute__((address_space(1))) const void gvoid_t;
typedef __attribute__((address_space(3))) void lvoid_t;

static __device__ __forceinline__ u16 f2bf(float f) {
    union { float f; uint32_t u; } v; v.f = f;
    uint32_t u = v.u;
    u += 0x7FFFu + ((u >> 16) & 1);   // RTNE (finite values only)
    return (u16)(u >> 16);
}

// ---------------------------------------------------------------------------
// Build B^T (bf16) with interleaved K: BmT32[n*256 + d] = pack(W1[d][n], W2[d][n])
// ---------------------------------------------------------------------------
__global__ __launch_bounds__(256) void k_bmat(const float* __restrict__ W1,
                                              const float* __restrict__ W2,
                                              uint32_t* __restrict__ BmT32) {
    const int n = blockIdx.x;
    const int d = threadIdx.x;
    float w1 = W1[d * DIM + n];
    float w2 = W2[d * DIM + n];
    BmT32[n * DIM + d] = (uint32_t)f2bf(w1) | ((uint32_t)f2bf(w2) << 16);
}

// ---------------------------------------------------------------------------
// FIR conv: h[t] = sum_{l=1..40} (mw[l]-mw[0]) * x[t-l]; writes interleaved
// bf16 A rows (x|h) into Aout (== d_out reused as scratch); column sums -> total.
// Block: 256 threads (one per d), covers 128 timesteps of one batch.
// ---------------------------------------------------------------------------
#define TCHUNK 128
__global__ __launch_bounds__(256) void k_conv(const float* __restrict__ x,
                                              const float* __restrict__ mw,
                                              uint32_t* __restrict__ Aout,
                                              float* __restrict__ total) {
    const int d = threadIdx.x;
    const int b = blockIdx.y;
    const int t0 = blockIdx.x * TCHUNK;

    const float mw0 = mw[d];
    float wp[MEM];
#pragma unroll
    for (int l = 0; l < MEM; ++l) wp[l] = mw[(l + 1) * DIM + d] - mw0;

    const float* xb = x + (size_t)b * SEQ * DIM;
    uint32_t* Ab = Aout + (size_t)b * SEQ * DIM;

    float hist[MEM];
#pragma unroll
    for (int j = 0; j < MEM; ++j) {
        int t = t0 - MEM + j;
        hist[j] = (t >= 0) ? xb[(size_t)t * DIM + d] : 0.0f;
    }

    float colsum = 0.0f;
    for (int s = 0; s < TCHUNK / 8; ++s) {
        const int t = t0 + s * 8;
        float cur[8];
#pragma unroll
        for (int i = 0; i < 8; ++i) cur[i] = xb[(size_t)(t + i) * DIM + d];
#pragma unroll
        for (int i = 0; i < 8; ++i) colsum += cur[i];

        float h[8];
#pragma unroll
        for (int i = 0; i < 8; ++i) {
            float acc = 0.0f;
#pragma unroll
            for (int l = 1; l <= MEM; ++l) {
                float v = (i - l >= 0) ? cur[i - l] : hist[MEM + i - l];
                acc += wp[l - 1] * v;
            }
            h[i] = acc;
        }
#pragma unroll
        for (int i = 0; i < 8; ++i) {
            uint32_t pack = (uint32_t)f2bf(cur[i]) | ((uint32_t)f2bf(h[i]) << 16);
            Ab[(size_t)(t + i) * DIM + d] = pack;
        }
        // slide history window by 8
#pragma unroll
        for (int j = 0; j < MEM - 8; ++j) hist[j] = hist[j + 8];
#pragma unroll
        for (int i = 0; i < 8; ++i) hist[MEM - 8 + i] = cur[i];
    }
    atomicAdd(&total[b * DIM + d], colsum);
}

// ---------------------------------------------------------------------------
// corr[b][n] = bias[n] + sum_d mw[0][d] * total[b][d] * W2[d][n]
// ---------------------------------------------------------------------------
__global__ __launch_bounds__(256) void k_corr(const float* __restrict__ W2,
                                              const float* __restrict__ bias,
                                              const float* __restrict__ mw,
                                              const float* __restrict__ total,
                                              float* __restrict__ corr) {
    const int b = blockIdx.x;
    const int n = threadIdx.x;
    float s = bias[n];
    for (int dd = 0; dd < DIM; ++dd)
        s += mw[dd] * total[b * DIM + dd] * W2[dd * DIM + n];
    corr[b * DIM + n] = s;
}

// ---------------------------------------------------------------------------
// GEMM: out[M=65536, N=256] = A[M, 512](bf16) @ Bmat[512, 256](bf16) + corr[b]
// BM=128, BN=256 (full width -> block reads only its own A rows, so A may live
// in d_out), BK=64, 8 waves (2x4), 16x16x32 bf16 MFMA, 4x4 frags per wave.
// ---------------------------------------------------------------------------
#define BM 128
#define BN 256
#define BK 64

__global__ __launch_bounds__(512) void k_gemm(const u16* A,
                                              const u16* __restrict__ BmT,
                                              const float* __restrict__ corr,
                                              float* out) {
    __shared__ __align__(16) u16 Alds[BM * BK];   // 16 KB, [row][k]
    __shared__ __align__(16) u16 Blds[BN * BK];   // 32 KB, [col][k]

    const int tid  = threadIdx.x;
    const int lane = tid & 63;
    const int w    = tid >> 6;     // 0..7
    const int wr   = w >> 2;       // 0..1  (M split)
    const int wc   = w & 3;        // 0..3  (N split)
    const int m0   = blockIdx.x * BM;

    f32x4 acc[4][4] = {};

    for (int kt = 0; kt < KTOT / BK; ++kt) {
        const int k0 = kt * BK;
        // ---- stage A tile [128][64] : 1024 x 16B chunks, 2 per thread
#pragma unroll
        for (int i = 0; i < 2; ++i) {
            int c   = i * 512 + tid;
            int row = c >> 3;
            int kin = (c & 7) * 8;
            const u16* g = A + ((size_t)(m0 + row) * KTOT + k0 + kin);
            char* l = (char*)Alds + (size_t)(i * 512 + (tid & ~63)) * 16;
            __builtin_amdgcn_global_load_lds((gvoid_t*)g, (lvoid_t*)l, 16, 0, 0);
        }
        // ---- stage B tile [256 cols][64 k] from BmT[n][k] : 2048 chunks, 4/thread
#pragma unroll
        for (int i = 0; i < 4; ++i) {
            int c   = i * 512 + tid;
            int n   = c >> 3;
            int kin = (c & 7) * 8;
            const u16* g = BmT + ((size_t)n * KTOT + k0 + kin);
            char* l = (char*)Blds + (size_t)(i * 512 + (tid & ~63)) * 16;
            __builtin_amdgcn_global_load_lds((gvoid_t*)g, (lvoid_t*)l, 16, 0, 0);
        }
        __syncthreads();

#pragma unroll
        for (int kk = 0; kk < 2; ++kk) {
            short8 af[4], bfr[4];
#pragma unroll
            for (int mi = 0; mi < 4; ++mi) {
                int r = wr * 64 + mi * 16 + (lane & 15);
                af[mi] = *(const short8*)(Alds + r * BK + kk * 32 + ((lane >> 4) * 8));
            }
#pragma unroll
            for (int ni = 0; ni < 4; ++ni) {
                int ccol = wc * 64 + ni * 16 + (lane & 15);
                bfr[ni] = *(const short8*)(Blds + ccol * BK + kk * 32 + ((lane >> 4) * 8));
            }
#pragma unroll
            for (int mi = 0; mi < 4; ++mi)
#pragma unroll
                for (int ni = 0; ni < 4; ++ni)
                    acc[mi][ni] = __builtin_amdgcn_mfma_f32_16x16x32_bf16(
                        af[mi], bfr[ni], acc[mi][ni], 0, 0, 0);
        }
        __syncthreads();
    }

    // ---- epilogue: out = acc + corr[b][col]
    const int bidx = m0 >> 12;           // 4096 rows per batch, BM=128 divides it
    const float* corr_b = corr + bidx * DIM;
#pragma unroll
    for (int ni = 0; ni < 4; ++ni) {
        int col = wc * 64 + ni * 16 + (lane & 15);
        float cv = corr_b[col];
#pragma unroll
        for (int mi = 0; mi < 4; ++mi) {
            int rbase = m0 + wr * 64 + mi * 16 + ((lane >> 4) * 4);
#pragma unroll
            for (int j = 0; j < 4; ++j)
                out[(size_t)(rbase + j) * DIM + col] = acc[mi][ni][j] + cv;
        }
    }
}

// ---------------------------------------------------------------------------
extern "C" void kernel_launch(void* const* d_in, const int* in_sizes, int n_in,
                              void* d_out, int out_size, void* d_ws, size_t ws_size,
                              hipStream_t stream) {
    const float* x    = (const float*)d_in[0];
    const float* W1   = (const float*)d_in[1];
    const float* W2   = (const float*)d_in[2];
    const float* bias = (const float*)d_in[3];
    const float* mw   = (const float*)d_in[4];
    float* out = (float*)d_out;

    // ws layout: BmT (256*512*2 = 256KB) | total (16KB) | corr (16KB)
    u16*   BmT   = (u16*)d_ws;
    float* total = (float*)((char*)d_ws + 262144);
    float* corr  = (float*)((char*)d_ws + 262144 + 16384);

    hipMemsetAsync(total, 0, NBATCH * DIM * sizeof(float), stream);
    k_bmat<<<dim3(DIM), dim3(256), 0, stream>>>(W1, W2, (uint32_t*)BmT);
    k_conv<<<dim3(SEQ / TCHUNK, NBATCH), dim3(256), 0, stream>>>(
        x, mw, (uint32_t*)d_out, total);
    k_corr<<<dim3(NBATCH), dim3(256), 0, stream>>>(W2, bias, mw, total, corr);
    k_gemm<<<dim3(MTOT / BM), dim3(512), 0, stream>>>(
        (const u16*)d_out, BmT, corr, out);
}